// Round 1
// baseline (3357.203 us; speedup 1.0000x reference)
//
#include <hip/hip_runtime.h>
#include <hip/hip_bf16.h>

// Problem constants
constexpr int B_ = 1024;     // batch
constexpr int D_ = 768;      // feature dim
constexpr int P_ = 100000;   // pool size
constexpr int K_ = 2;        // top-k

// Output layout (flat fp32):
//   [0, 786432)                    batched_prompt [B, D]
//   [786432]                       reduce_sim (scalar)
//   [786433, 786433+102400000)     similarity [B, P]
//   [103186433, 103186433+2048)    idx [B, 2] stored as float values
constexpr size_t OFF_BP  = 0;
constexpr size_t OFF_RS  = 786432;
constexpr size_t OFF_SIM = 786433;
constexpr size_t OFF_IDX = OFF_SIM + (size_t)B_ * P_;

// ---------------------------------------------------------------------------
// K1: normalize cls_features rows -> xn [B, D]. fp64 sum-of-squares for an
// (effectively) exactly-rounded row norm.
__global__ __launch_bounds__(64)
void k_norm_cls(const float* __restrict__ cls, float* __restrict__ xn) {
    const int b = blockIdx.x;
    const int l = threadIdx.x;
    float4 v[3];
    double ss = 0.0;
#pragma unroll
    for (int i = 0; i < 3; ++i) {
        v[i] = *reinterpret_cast<const float4*>(&cls[(size_t)b * D_ + (size_t)(l + 64 * i) * 4]);
        ss += (double)v[i].x * v[i].x + (double)v[i].y * v[i].y +
              (double)v[i].z * v[i].z + (double)v[i].w * v[i].w;
    }
#pragma unroll
    for (int off = 32; off; off >>= 1) ss += __shfl_xor(ss, off);
    const float rn = (float)(1.0 / sqrt(fmax(ss, 1e-12)));
#pragma unroll
    for (int i = 0; i < 3; ++i) {
        float4 o;
        o.x = v[i].x * rn; o.y = v[i].y * rn; o.z = v[i].z * rn; o.w = v[i].w * rn;
        *reinterpret_cast<float4*>(&xn[(size_t)b * D_ + (size_t)(l + 64 * i) * 4]) = o;
    }
}

// ---------------------------------------------------------------------------
// K2: per-row inverse norm of prompt_key -> rnorm [P]. One wave per row.
__global__ __launch_bounds__(256)
void k_norm_key(const float* __restrict__ key, float* __restrict__ rnorm) {
    const int row = blockIdx.x * 4 + (threadIdx.x >> 6);
    const int l = threadIdx.x & 63;
    const float* kr = key + (size_t)row * D_;
    double ss = 0.0;
#pragma unroll
    for (int i = 0; i < 3; ++i) {
        const float4 v = *reinterpret_cast<const float4*>(&kr[(size_t)(l + 64 * i) * 4]);
        ss += (double)v.x * v.x + (double)v.y * v.y + (double)v.z * v.z + (double)v.w * v.w;
    }
#pragma unroll
    for (int off = 32; off; off >>= 1) ss += __shfl_xor(ss, off);
    if (l == 0) rnorm[row] = (float)(1.0 / sqrt(fmax(ss, 1e-12)));
}

// ---------------------------------------------------------------------------
// K3: similarity GEMM: sim[b][p] = (xn[b] . key[p]) * rnorm[p].
// 64x64 block tile, BK=64, 256 threads, 4x4 micro-tile, transposed LDS
// (As[k][m], pad to 68 so ds_read_b128 stays 16B-aligned).
// Grid: x = 16 (m-blocks, fastest) so consecutive blocks share the B strip
// (L2/L3 reuse of the 307 MB key matrix).
__global__ __launch_bounds__(256)
void k_gemm(const float* __restrict__ xn, const float* __restrict__ key,
            const float* __restrict__ rnorm, float* __restrict__ sim) {
    __shared__ float As[64][68];
    __shared__ float Bs[64][68];
    const int bm0 = blockIdx.x * 64;
    const int bn0 = blockIdx.y * 64;
    const int tid = threadIdx.x;
    const int f    = tid & 15;   // k-chunk (float4) for loads
    const int mrow = tid >> 4;   // row base for loads
    const int tr = tid >> 4;     // 0..15 micro-tile row group
    const int tc = tid & 15;     // 0..15 micro-tile col group

    float acc[4][4] = {};

    for (int kk = 0; kk < D_; kk += 64) {
        __syncthreads();
#pragma unroll
        for (int it = 0; it < 4; ++it) {
            const int m = mrow + 16 * it;
            const float4 av = *reinterpret_cast<const float4*>(
                &xn[(size_t)(bm0 + m) * D_ + kk + f * 4]);
            As[f * 4 + 0][m] = av.x; As[f * 4 + 1][m] = av.y;
            As[f * 4 + 2][m] = av.z; As[f * 4 + 3][m] = av.w;
            const int n = bn0 + m;
            float4 bv = make_float4(0.f, 0.f, 0.f, 0.f);
            if (n < P_) bv = *reinterpret_cast<const float4*>(
                &key[(size_t)n * D_ + kk + f * 4]);
            Bs[f * 4 + 0][m] = bv.x; Bs[f * 4 + 1][m] = bv.y;
            Bs[f * 4 + 2][m] = bv.z; Bs[f * 4 + 3][m] = bv.w;
        }
        __syncthreads();
#pragma unroll 8
        for (int k = 0; k < 64; ++k) {
            const float4 a = *reinterpret_cast<const float4*>(&As[k][tr * 4]);
            const float4 b = *reinterpret_cast<const float4*>(&Bs[k][tc * 4]);
            const float av4[4] = {a.x, a.y, a.z, a.w};
            const float bv4[4] = {b.x, b.y, b.z, b.w};
#pragma unroll
            for (int i = 0; i < 4; ++i)
#pragma unroll
                for (int j = 0; j < 4; ++j)
                    acc[i][j] = fmaf(av4[i], bv4[j], acc[i][j]);
        }
    }

#pragma unroll
    for (int j = 0; j < 4; ++j) {
        const int n = bn0 + tc * 4 + j;
        if (n < P_) {
            const float rn = rnorm[n];
#pragma unroll
            for (int i = 0; i < 4; ++i) {
                sim[(size_t)(bm0 + tr * 4 + i) * P_ + n] = acc[i][j] * rn;
            }
        }
    }
}

// ---------------------------------------------------------------------------
// K4: per-row approximate top-8 candidates (value-ordered, tie -> lower index).
__global__ __launch_bounds__(256)
void k_top8(const float* __restrict__ sim, int* __restrict__ cand_i) {
    __shared__ float sv[256][8];
    __shared__ int   si[256][8];
    const int b = blockIdx.x;
    const int tid = threadIdx.x;
    const float* row = sim + (size_t)b * P_;

    float v[8]; int ix[8];
#pragma unroll
    for (int i = 0; i < 8; ++i) { v[i] = -1e30f; ix[i] = 0x7fffffff; }

    for (int p = tid; p < P_; p += 256) {
        const float s = row[p];
        if (s > v[7]) {
            int j = 7;
            while (j > 0 && s > v[j - 1]) { v[j] = v[j - 1]; ix[j] = ix[j - 1]; --j; }
            v[j] = s; ix[j] = p;
        }
    }
#pragma unroll
    for (int i = 0; i < 8; ++i) { sv[tid][i] = v[i]; si[tid][i] = ix[i]; }

    for (int stride = 128; stride >= 1; stride >>= 1) {
        __syncthreads();
        if (tid < stride) {
            const int o = tid + stride;
            float ov[8]; int oi[8];
            int ia = 0, ib = 0;
#pragma unroll
            for (int t = 0; t < 8; ++t) {
                bool takeA;
                if (ia >= 8)      takeA = false;
                else if (ib >= 8) takeA = true;
                else {
                    const float avv = sv[tid][ia], bvv = sv[o][ib];
                    takeA = (avv > bvv) || (avv == bvv && si[tid][ia] < si[o][ib]);
                }
                if (takeA) { ov[t] = sv[tid][ia]; oi[t] = si[tid][ia]; ++ia; }
                else       { ov[t] = sv[o][ib];   oi[t] = si[o][ib];   ++ib; }
            }
            __syncthreads();
#pragma unroll
            for (int t = 0; t < 8; ++t) { sv[tid][t] = ov[t]; si[tid][t] = oi[t]; }
        } else {
            __syncthreads();
            __syncthreads();
        }
    }
    __syncthreads();
    if (tid < 8) cand_i[b * 8 + tid] = si[0][tid];
}

// ---------------------------------------------------------------------------
// K5: exact fp64 refinement of the 8 candidates; pick true top-2 of the
// fp32-rounded normalized inputs. Writes idx (as float), selected ints,
// and per-row (v0+v1) for reduce_sim.
__global__ __launch_bounds__(256)
void k_refine(const float* __restrict__ xn, const float* __restrict__ key,
              const float* __restrict__ rnorm, const int* __restrict__ cand_i,
              float* __restrict__ idx_out, int* __restrict__ sel,
              float* __restrict__ rowsum) {
    const int b = blockIdx.x;
    const int c = threadIdx.x >> 5;   // candidate 0..7
    const int l = threadIdx.x & 31;
    const int p = cand_i[b * 8 + c];
    const float rp = rnorm[p];
    double acc = 0.0;
    for (int d = l; d < D_; d += 32) {
        const float pn = key[(size_t)p * D_ + d] * rp;  // fp32-rounded prompt_norm
        acc += (double)xn[(size_t)b * D_ + d] * (double)pn;
    }
#pragma unroll
    for (int off = 16; off; off >>= 1) acc += __shfl_down(acc, off, 32);

    __shared__ double dv[8];
    __shared__ int    dpi[8];
    if (l == 0) { dv[c] = acc; dpi[c] = p; }
    __syncthreads();
    if (threadIdx.x == 0) {
        double v0 = -1e300, v1 = -1e300;
        int i0 = 0x7fffffff, i1 = 0x7fffffff;
        for (int c2 = 0; c2 < 8; ++c2) {
            const double v = dv[c2]; const int pp = dpi[c2];
            if (v > v0 || (v == v0 && pp < i0)) { v1 = v0; i1 = i0; v0 = v; i0 = pp; }
            else if (v > v1 || (v == v1 && pp < i1)) { v1 = v; i1 = pp; }
        }
        idx_out[b * 2 + 0] = (float)i0;
        idx_out[b * 2 + 1] = (float)i1;
        sel[b * 2 + 0] = i0;
        sel[b * 2 + 1] = i1;
        rowsum[b] = (float)(v0 + v1);
    }
}

// ---------------------------------------------------------------------------
// K6: batched_prompt[b] = 0.5*(prompt[i0] + prompt[i1]) + cls[b]
__global__ __launch_bounds__(192)
void k_gather(const float* __restrict__ prompt, const float* __restrict__ cls,
              const int* __restrict__ sel, float* __restrict__ bp) {
    const int b = blockIdx.x;
    const int t = threadIdx.x;   // 192 float4 per row
    const int i0 = sel[b * 2 + 0];
    const int i1 = sel[b * 2 + 1];
    const float4 p0 = *reinterpret_cast<const float4*>(&prompt[(size_t)i0 * D_ + (size_t)t * 4]);
    const float4 p1 = *reinterpret_cast<const float4*>(&prompt[(size_t)i1 * D_ + (size_t)t * 4]);
    const float4 cv = *reinterpret_cast<const float4*>(&cls[(size_t)b * D_ + (size_t)t * 4]);
    float4 o;
    o.x = 0.5f * (p0.x + p1.x) + cv.x;
    o.y = 0.5f * (p0.y + p1.y) + cv.y;
    o.z = 0.5f * (p0.z + p1.z) + cv.z;
    o.w = 0.5f * (p0.w + p1.w) + cv.w;
    *reinterpret_cast<float4*>(&bp[(size_t)b * D_ + (size_t)t * 4]) = o;
}

// ---------------------------------------------------------------------------
// K7: reduce_sim = sum(rowsum) / B
__global__ __launch_bounds__(256)
void k_rsum(const float* __restrict__ rowsum, float* __restrict__ out) {
    __shared__ float sh[256];
    float a = 0.f;
    for (int i = threadIdx.x; i < B_; i += 256) a += rowsum[i];
    sh[threadIdx.x] = a;
    __syncthreads();
    for (int s = 128; s; s >>= 1) {
        if (threadIdx.x < s) sh[threadIdx.x] += sh[threadIdx.x + s];
        __syncthreads();
    }
    if (threadIdx.x == 0) out[0] = sh[0] / (float)B_;
}

// ---------------------------------------------------------------------------
extern "C" void kernel_launch(void* const* d_in, const int* in_sizes, int n_in,
                              void* d_out, int out_size, void* d_ws, size_t ws_size,
                              hipStream_t stream) {
    const float* cls    = (const float*)d_in[0];
    const float* prompt = (const float*)d_in[1];
    const float* key    = (const float*)d_in[2];
    float* out  = (float*)d_out;
    float* bp   = out + OFF_BP;
    float* rs   = out + OFF_RS;
    float* sim  = out + OFF_SIM;
    float* idxf = out + OFF_IDX;

    char* w = (char*)d_ws;
    float* xn     = (float*)w;  w += (size_t)B_ * D_ * 4;      // 3.0 MB
    float* rnorm  = (float*)w;  w += (size_t)P_ * 4;           // 0.4 MB
    int*   cand_i = (int*)w;    w += (size_t)B_ * 8 * 4;
    int*   sel    = (int*)w;    w += (size_t)B_ * 2 * 4;
    float* rowsum = (float*)w;  w += (size_t)B_ * 4;

    k_norm_cls<<<B_, 64, 0, stream>>>(cls, xn);
    k_norm_key<<<P_ / 4, 256, 0, stream>>>(key, rnorm);
    k_gemm<<<dim3(B_ / 64, (P_ + 63) / 64), 256, 0, stream>>>(xn, key, rnorm, sim);
    k_top8<<<B_, 256, 0, stream>>>(sim, cand_i);
    k_refine<<<B_, 256, 0, stream>>>(xn, key, rnorm, cand_i, idxf, sel, rowsum);
    k_gather<<<B_, 192, 0, stream>>>(prompt, cls, sel, bp);
    k_rsum<<<1, 256, 0, stream>>>(rowsum, rs);
}